// Round 1
// baseline (43.044 us; speedup 1.0000x reference)
//
#include <hip/hip_runtime.h>
#include <hip/hip_bf16.h>

// Problem constants
#define BM_OUT   7       // softpool batch-out: (16-4)/2+1
#define LM_OUT   256     // (512-2)/2+1
#define DM_OUT   512     // (1024-2)/2+1
#define SP_ELEMS (BM_OUT*LM_OUT*DM_OUT)        // 917504 per tensor
#define M_ROWS   (BM_OUT*LM_OUT)               // 1792
#define NCOLS    512
#define KDIM     512
#define OUT_FEAT_SZ (M_ROWS*1024)              // 1835008
#define OUT_HAT_SZ  (M_ROWS*512)               // 917504

typedef __attribute__((ext_vector_type(8))) __bf16 bf16x8;
typedef __attribute__((ext_vector_type(4))) float  f32x4;

__device__ __forceinline__ unsigned short f2bf(float f) {
    union { float f; unsigned int u; } v; v.f = f;
    unsigned int r = v.u + 0x7fffu + ((v.u >> 16) & 1u);   // RNE
    return (unsigned short)(r >> 16);
}

// SoftPool3D over (4,2,2) windows, stride (2,2,2), VALID, on [16,512,1024].
// One thread -> 2 consecutive d' outputs (one float4 of input D per (b,l) tap).
// blockIdx.y selects tensor (0: x, 1: y).
__global__ __launch_bounds__(256) void softpool_k(
    const float* __restrict__ x, const float* __restrict__ y,
    float* __restrict__ xo, float* __restrict__ yo)
{
    const float* in  = blockIdx.y ? y  : x;
    float*       out = blockIdx.y ? yo : xo;
    int t = blockIdx.x * 256 + threadIdx.x;   // 458752 threads per tensor
    int u = t & 255;          // d'-pair index (d' = 2u, 2u+1)
    int l = (t >> 8) & 255;   // l'
    int b = t >> 16;          // b' 0..6
    const float* base = in + ((size_t)(2*b) * 512 + 2*l) * 1024 + 4*u;
    float num0=0.f, den0=0.f, num1=0.f, den1=0.f;
    #pragma unroll
    for (int i = 0; i < 4; ++i) {
        #pragma unroll
        for (int j = 0; j < 2; ++j) {
            float4 v = *reinterpret_cast<const float4*>(base + ((size_t)(i*512 + j))*1024);
            float e0=__expf(v.x), e1=__expf(v.y), e2=__expf(v.z), e3=__expf(v.w);
            num0 += e0*v.x + e1*v.y;  den0 += e0 + e1;
            num1 += e2*v.z + e3*v.w;  den1 += e2 + e3;
        }
    }
    float2 o; o.x = num0/den0; o.y = num1/den1;
    *reinterpret_cast<float2*>(out + (size_t)t*2) = o;
}

// f32 -> bf16 weight conversion (262144 elems each; blockIdx.y picks tensor)
__global__ __launch_bounds__(256) void cvt_k(
    const float* __restrict__ a, const float* __restrict__ b,
    unsigned short* __restrict__ oa, unsigned short* __restrict__ ob)
{
    const float* s = blockIdx.y ? b : a;
    unsigned short* d = blockIdx.y ? ob : oa;
    int i = blockIdx.x * 256 + threadIdx.x;   // 65536 threads, 4 elems each
    float4 v = reinterpret_cast<const float4*>(s)[i];
    ushort4 o; o.x=f2bf(v.x); o.y=f2bf(v.y); o.z=f2bf(v.z); o.w=f2bf(v.w);
    reinterpret_cast<ushort4*>(d)[i] = o;
}

// Fused: C = A @ W^T + bias (+ residual A for side 0), row-softmax over N=512,
// write hat and 0.5-scaled half of feature. Block: 16 rows x full N=512.
// 4 waves; wave w owns cols [w*128, w*128+128).
__global__ __launch_bounds__(256) void gemm_sm_k(
    const float* __restrict__ x_sp, const float* __restrict__ y_sp,
    const unsigned short* __restrict__ wv_bf, const unsigned short* __restrict__ wt_bf,
    const float* __restrict__ b_v, const float* __restrict__ b_t,
    const float* __restrict__ wvec, float* __restrict__ d_out)
{
    const int side = blockIdx.y;
    const float* A            = side ? y_sp  : x_sp;
    const unsigned short* B   = side ? wt_bf : wv_bf;
    const float* bias         = side ? b_t   : b_v;
    const float* res          = side ? nullptr : x_sp;
    const int mbase = blockIdx.x * 16;

    __shared__ unsigned short tA[16 * 520];   // bf16 A tile, padded stride
    __shared__ float logits[16 * 516];        // padded stride

    // stage A block (16x512 f32 -> bf16 LDS)
    {
        const float* Ab = A + (size_t)mbase * KDIM;
        #pragma unroll
        for (int r = 0; r < 8; ++r) {
            int f4  = threadIdx.x + 256*r;     // 0..2047
            float4 v = reinterpret_cast<const float4*>(Ab)[f4];
            int row = f4 >> 7;                 // 128 float4 per row
            int col = (f4 & 127) << 2;
            ushort4 o; o.x=f2bf(v.x); o.y=f2bf(v.y); o.z=f2bf(v.z); o.w=f2bf(v.w);
            *reinterpret_cast<ushort4*>(&tA[row*520 + col]) = o;
        }
    }
    __syncthreads();

    const int lane = threadIdx.x & 63;
    const int wid  = threadIdx.x >> 6;
    const int arow = lane & 15;
    const int kq   = lane >> 4;    // 0..3
    const int nb   = wid * 128;

    f32x4 acc[8];
    #pragma unroll
    for (int t = 0; t < 8; ++t) acc[t] = (f32x4){0.f, 0.f, 0.f, 0.f};

    #pragma unroll 2
    for (int ks = 0; ks < 16; ++ks) {
        int kk = ks*32 + kq*8;
        bf16x8 af = *reinterpret_cast<const bf16x8*>(&tA[arow*520 + kk]);
        #pragma unroll
        for (int t = 0; t < 8; ++t) {
            const unsigned short* bp = B + (size_t)(nb + t*16 + arow) * KDIM + kk;
            bf16x8 bf = *reinterpret_cast<const bf16x8*>(bp);
            acc[t] = __builtin_amdgcn_mfma_f32_16x16x32_bf16(af, bf, acc[t], 0, 0, 0);
        }
    }

    // epilogue: logits (acc + bias + residual) -> LDS
    #pragma unroll
    for (int t = 0; t < 8; ++t) {
        int n = nb + t*16 + arow;
        float bn = bias[n];
        #pragma unroll
        for (int i = 0; i < 4; ++i) {
            int row = kq*4 + i;    // C/D: col=lane&15, row=(lane>>4)*4+i
            float v = acc[t][i] + bn;
            if (res) v += res[(size_t)(mbase + row) * KDIM + n];
            logits[row*516 + n] = v;
        }
    }
    __syncthreads();

    // block softmax: wave wid handles rows wid*4 .. wid*4+3 (full 512 cols)
    float ew0 = __expf(wvec[0]), ew1 = __expf(wvec[1]);
    float wsc = (side ? ew1 : ew0) / (ew0 + ew1);
    float* feat = d_out;
    float* hat  = d_out + OUT_FEAT_SZ + (size_t)side * OUT_HAT_SZ;

    for (int r = 0; r < 4; ++r) {
        int row = wid*4 + r;
        int m = mbase + row;
        const float* lp = &logits[row*516 + lane*8];
        float4 v0 = *reinterpret_cast<const float4*>(lp);
        float4 v1 = *reinterpret_cast<const float4*>(lp + 4);
        float mx = fmaxf(fmaxf(fmaxf(v0.x,v0.y), fmaxf(v0.z,v0.w)),
                         fmaxf(fmaxf(v1.x,v1.y), fmaxf(v1.z,v1.w)));
        #pragma unroll
        for (int s = 32; s; s >>= 1) mx = fmaxf(mx, __shfl_xor(mx, s));
        float e0=__expf(v0.x-mx), e1=__expf(v0.y-mx), e2=__expf(v0.z-mx), e3=__expf(v0.w-mx);
        float e4=__expf(v1.x-mx), e5=__expf(v1.y-mx), e6=__expf(v1.z-mx), e7=__expf(v1.w-mx);
        float sum = ((e0+e1)+(e2+e3)) + ((e4+e5)+(e6+e7));
        #pragma unroll
        for (int s = 32; s; s >>= 1) sum += __shfl_xor(sum, s);
        float inv = 1.f / sum;
        float4 p0 = {e0*inv, e1*inv, e2*inv, e3*inv};
        float4 p1 = {e4*inv, e5*inv, e6*inv, e7*inv};
        *reinterpret_cast<float4*>(&hat[(size_t)m*512 + lane*8])     = p0;
        *reinterpret_cast<float4*>(&hat[(size_t)m*512 + lane*8 + 4]) = p1;
        float4 f0 = {p0.x*wsc, p0.y*wsc, p0.z*wsc, p0.w*wsc};
        float4 f1 = {p1.x*wsc, p1.y*wsc, p1.z*wsc, p1.w*wsc};
        size_t fo = (size_t)m*1024 + side*512 + lane*8;
        *reinterpret_cast<float4*>(&feat[fo])     = f0;
        *reinterpret_cast<float4*>(&feat[fo + 4]) = f1;
    }
}

extern "C" void kernel_launch(void* const* d_in, const int* in_sizes, int n_in,
                              void* d_out, int out_size, void* d_ws, size_t ws_size,
                              hipStream_t stream)
{
    const float* x        = (const float*)d_in[0];
    const float* y        = (const float*)d_in[1];
    const float* w_fc2_t  = (const float*)d_in[12];
    const float* b_fc2_t  = (const float*)d_in[13];
    const float* w_fc2_v  = (const float*)d_in[14];
    const float* b_fc2_v  = (const float*)d_in[15];
    const float* wvec     = (const float*)d_in[18];

    float* x_sp = (float*)d_ws;                     // 917504 f32
    float* y_sp = x_sp + SP_ELEMS;                  // 917504 f32
    unsigned short* wv_bf = (unsigned short*)(y_sp + SP_ELEMS);  // 262144 bf16
    unsigned short* wt_bf = wv_bf + 262144;         // 262144 bf16

    // 1) softpool both inputs
    softpool_k<<<dim3(1792, 2), 256, 0, stream>>>(x, y, x_sp, y_sp);
    // 2) weights -> bf16
    cvt_k<<<dim3(256, 2), 256, 0, stream>>>(w_fc2_v, w_fc2_t, wv_bf, wt_bf);
    // 3) fused fc2 + residual + softmax + concat
    gemm_sm_k<<<dim3(M_ROWS/16, 2), 256, 0, stream>>>(
        x_sp, y_sp, wv_bf, wt_bf, b_fc2_v, b_fc2_t, wvec, (float*)d_out);
}